// Round 19
// baseline (125.514 us; speedup 1.0000x reference)
//
#include <hip/hip_runtime.h>
#include <hip/hip_bf16.h>
#include <cstddef>

#define N_FEATS 64
#define NBKT_SHIFT 8       // coarse bucket = dst >> 8 (256 nodes per bucket)
#define EPB 4096           // edges per split block
#define CAP 6144           // per-bucket region capacity (mean 4081, ~32 sigma)
// NOTE: requires N <= 65536 (src fits u16). Here N = 50000.

typedef __attribute__((ext_vector_type(8))) short bf16x8;
typedef __attribute__((ext_vector_type(4))) float f32x4;

// round-to-nearest-even f32 -> bf16 bits
__device__ __forceinline__ unsigned f2bf(float f) {
    unsigned x = __float_as_uint(f);
    return (x + 0x7fffu + ((x >> 16) & 1u)) >> 16;
}

// ---------------------------------------------------------------------------
// k_init (1 block): combined weights + bias vector + zero cursors & barrier.
//   Wc[64][32] = [Wl1@Wl2 | Wl1@Wr2 | Wr1@Wl2 | Wr1@Wr2]  (bf16)
//   bvec[16]   = [bl1@Wl2 | bl1@Wr2 + bl2]                 (f32)
// (NOT a hipMemsetAsync: runtime fill kernel for tiny buffers costs ~40 us
//  per dispatch in this graph — measured round 16.)
// ---------------------------------------------------------------------------
__global__ __launch_bounds__(256) void k_init(
        const float* __restrict__ Wl1, const float* __restrict__ bl1,
        const float* __restrict__ Wr1, const float* __restrict__ Wl2,
        const float* __restrict__ bl2, const float* __restrict__ Wr2,
        unsigned short* __restrict__ Wc, float* __restrict__ bvec,
        int* __restrict__ cursor, int* __restrict__ barrier, int nbkt) {
    int tid = threadIdx.x;
    int k = tid & 63, jg = tid >> 6;
    const float* W1 = (jg < 2) ? Wl1 : Wr1;
    const float* W2 = (jg & 1) ? Wr2 : Wl2;
    float acc[8] = {0.f,0.f,0.f,0.f,0.f,0.f,0.f,0.f};
    for (int m = 0; m < 64; ++m) {
        float w1 = W1[k * 64 + m];
        #pragma unroll
        for (int jj = 0; jj < 8; ++jj) acc[jj] += w1 * W2[m * 8 + jj];
    }
    #pragma unroll
    for (int jj = 0; jj < 8; ++jj)
        Wc[k * 32 + jg * 8 + jj] = (unsigned short)f2bf(acc[jj]);
    if (tid < 16) {
        const float* W2b = (tid < 8) ? Wl2 : Wr2;
        float a = 0.f;
        for (int m = 0; m < 64; ++m) a += bl1[m] * W2b[m * 8 + (tid & 7)];
        if (tid >= 8) a += bl2[tid - 8];
        bvec[tid] = a;
    }
    if (tid < nbkt) cursor[tid] = 0;
    if (tid == 0) *barrier = 0;
}

// ---------------------------------------------------------------------------
// Fused dispatch: blocks < nb1 split edges into fixed-CAP bucket regions
// (LDS stage + count, one global reservation atomic per bucket per block).
// Blocks >= nb1 run the MFMA GEMM  Y = X@Wc -> G (bf16 s|s'), T (f32 t|t').
// ---------------------------------------------------------------------------
__global__ __launch_bounds__(256) void k_split_gemm(
        const int* __restrict__ src, const int* __restrict__ dst,
        int* __restrict__ cursor, unsigned* __restrict__ pairs,
        int nEdges, int nbkt, int nb1,
        const float* __restrict__ x,
        const unsigned short* __restrict__ Wc,
        const float* __restrict__ bvec,
        unsigned short* __restrict__ G,   // bf16 [N][16] = [s|s']
        float* __restrict__ T,            // f32  [N][16] = [t|t'] (+bias)
        int nNodes, int nStrips) {
    __shared__ unsigned spr[EPB];
    __shared__ int lh[256];
    __shared__ int lcur[256];
    int tid = threadIdx.x, b = blockIdx.x;

    if (b < nb1) {
        lh[tid] = 0;
        __syncthreads();
        int base = b * EPB;
        int m = nEdges - base; if (m > EPB) m = EPB;
        for (int j = tid; j < m; j += 256) {
            unsigned d = (unsigned)dst[base + j];
            spr[j] = ((unsigned)src[base + j] << 16) | d;
            atomicAdd(&lh[d >> NBKT_SHIFT], 1);
        }
        __syncthreads();
        if (tid < nbkt) lcur[tid] = atomicAdd(&cursor[tid], lh[tid]);
        __syncthreads();
        for (int j = tid; j < m; j += 256) {
            unsigned pr = spr[j];
            unsigned d = pr & 0xffffu;
            int bkt = d >> NBKT_SHIFT;
            int pos = atomicAdd(&lcur[bkt], 1);
            if (pos < CAP)
                pairs[(size_t)bkt * CAP + pos] = ((pr >> 16) << 8) | (d & 255u);
        }
        return;
    }

    // ---- MFMA GEMM ----
    int w  = tid >> 6;
    int l  = tid & 63;
    int fc = l & 15;
    int kg = l >> 4;
    bf16x8 bf[2][2];
    #pragma unroll
    for (int ct = 0; ct < 2; ++ct)
        #pragma unroll
        for (int kh = 0; kh < 2; ++kh)
            #pragma unroll
            for (int i = 0; i < 8; ++i) {
                int k = kh * 32 + kg * 8 + i;
                bf[ct][kh][i] = (short)Wc[k * 32 + ct * 16 + fc];
            }
    float bias = bvec[fc];

    for (int strip = b - nb1; strip < nStrips; strip += gridDim.x - nb1) {
        int node0 = strip * 64;
        int arow = node0 + w * 16 + fc;
        int ar = (arow < nNodes) ? arow : (nNodes - 1);
        const float* xp = x + (size_t)ar * 64 + kg * 8;
        float4 xa = *(const float4*)(xp);
        float4 xb = *(const float4*)(xp + 4);
        float4 xc = *(const float4*)(xp + 32);
        float4 xd = *(const float4*)(xp + 36);
        bf16x8 a0, a1;
        a0[0]=(short)f2bf(xa.x); a0[1]=(short)f2bf(xa.y);
        a0[2]=(short)f2bf(xa.z); a0[3]=(short)f2bf(xa.w);
        a0[4]=(short)f2bf(xb.x); a0[5]=(short)f2bf(xb.y);
        a0[6]=(short)f2bf(xb.z); a0[7]=(short)f2bf(xb.w);
        a1[0]=(short)f2bf(xc.x); a1[1]=(short)f2bf(xc.y);
        a1[2]=(short)f2bf(xc.z); a1[3]=(short)f2bf(xc.w);
        a1[4]=(short)f2bf(xd.x); a1[5]=(short)f2bf(xd.y);
        a1[6]=(short)f2bf(xd.z); a1[7]=(short)f2bf(xd.w);

        f32x4 d0 = {0.f, 0.f, 0.f, 0.f};
        f32x4 d1 = {0.f, 0.f, 0.f, 0.f};
        d0 = __builtin_amdgcn_mfma_f32_16x16x32_bf16(a0, bf[0][0], d0, 0, 0, 0);
        d0 = __builtin_amdgcn_mfma_f32_16x16x32_bf16(a1, bf[0][1], d0, 0, 0, 0);
        d1 = __builtin_amdgcn_mfma_f32_16x16x32_bf16(a0, bf[1][0], d1, 0, 0, 0);
        d1 = __builtin_amdgcn_mfma_f32_16x16x32_bf16(a1, bf[1][1], d1, 0, 0, 0);

        #pragma unroll
        for (int r = 0; r < 4; ++r) {
            int node = node0 + w * 16 + kg * 4 + r;
            if (node < nNodes) {
                G[(size_t)node * 16 + fc] = (unsigned short)f2bf(d0[r]);
                T[(size_t)node * 16 + fc] = d1[r] + bias;
            }
        }
    }
}

// ---------------------------------------------------------------------------
// Fused sort + layer-1 gather + grid-barrier + final: one 1024-thread block
// per bucket (196 blocks, all co-resident: 16 waves/block <= 32/CU, 16KB LDS).
// Phase A: counting sort by dst&255 -> LDS ss[] (no global CSR needed).
// Phase B: 16 waves x 2 nodes: p = mean-gather(G[s])+t -> pbf (bf16),
//          q = mean-gather(G[s'])+t' (f32).
// Barrier: per-thread __threadfence (device-release) + arrive/spin on LLC
//          atomic counter. Co-residency guaranteed (196 blocks <= 256 CUs).
// Phase C: out = mean-gather(pbf[src]) + q, edge lists from LDS ss.
// ---------------------------------------------------------------------------
__global__ __launch_bounds__(1024) void k_fg_final(
        const unsigned* __restrict__ pairs,
        const int* __restrict__ cursor,
        const unsigned* __restrict__ G,     // [N][8] uints (16 bf16)
        const float* __restrict__ T,        // [N][16]
        unsigned* __restrict__ pbf,         // [N][4] uints (8 bf16)
        float* __restrict__ q,              // [N][8]
        int* __restrict__ barrier,
        float* __restrict__ out,
        int nNodes, int nbkt) {
    __shared__ unsigned short ss[CAP];
    __shared__ int cntA[256];
    __shared__ int scanbuf[256];
    __shared__ int loff[256];
    __shared__ int cur[256];
    int tid = threadIdx.x, b = blockIdx.x;
    int bStart = b * CAP;
    int m = cursor[b]; if (m > CAP) m = CAP;

    // ---- Phase A: counting sort into LDS ----
    if (tid < 256) cntA[tid] = 0;
    __syncthreads();
    for (int e = tid; e < m; e += 1024)
        atomicAdd(&cntA[pairs[bStart + e] & 255u], 1);
    __syncthreads();
    int v = 0;
    if (tid < 256) { v = cntA[tid]; scanbuf[tid] = v; }
    __syncthreads();
    for (int d = 1; d < 256; d <<= 1) {
        int t = (tid < 256 && tid >= d) ? scanbuf[tid - d] : 0;
        __syncthreads();
        if (tid < 256) scanbuf[tid] += t;
        __syncthreads();
    }
    if (tid < 256) {
        int excl = scanbuf[tid] - v;
        loff[tid] = excl;
        cur[tid] = excl;
    }
    __syncthreads();
    for (int e = tid; e < m; e += 1024) {
        unsigned pr = pairs[bStart + e];
        int pos = atomicAdd(&cur[pr & 255u], 1);
        ss[pos] = (unsigned short)(pr >> 8);
    }
    __syncthreads();

    int wave = tid >> 6, lane = tid & 63;

    // ---- Phase B: gather2 (2 nodes/wave, 16 waves -> 32 nodes/iter) ----
    {
        int half = lane >> 5;
        int eg   = (lane >> 2) & 7;   // 8 edge groups
        int t4   = lane & 3;          // uint2 slot (8B)
        const uint2* G2 = (const uint2*)G;

        #pragma unroll 1
        for (int it = 0; it < 8; ++it) {
            int nl = it * 32 + wave * 2 + half;
            int node = (b << NBKT_SHIFT) + nl;
            if (node >= nNodes) continue;
            int cnt_n = cntA[nl];
            int lo = loff[nl];

            float a0 = 0.f, a1 = 0.f, a2 = 0.f, a3 = 0.f;
            int id = (eg < cnt_n) ? (int)ss[lo + eg] : -1;
            for (int base = 0; base < cnt_n; base += 8) {
                int en = base + 8 + eg;
                int idn = (en < cnt_n) ? (int)ss[lo + en] : -1;
                if (id >= 0) {
                    uint2 r = G2[(size_t)id * 4 + t4];
                    a0 += __uint_as_float(r.x << 16);
                    a1 += __uint_as_float(r.x & 0xffff0000u);
                    a2 += __uint_as_float(r.y << 16);
                    a3 += __uint_as_float(r.y & 0xffff0000u);
                }
                id = idn;
            }
            a0 += __shfl_xor(a0, 4);  a1 += __shfl_xor(a1, 4);
            a2 += __shfl_xor(a2, 4);  a3 += __shfl_xor(a3, 4);
            a0 += __shfl_xor(a0, 8);  a1 += __shfl_xor(a1, 8);
            a2 += __shfl_xor(a2, 8);  a3 += __shfl_xor(a3, 8);
            a0 += __shfl_xor(a0, 16); a1 += __shfl_xor(a1, 16);
            a2 += __shfl_xor(a2, 16); a3 += __shfl_xor(a3, 16);

            if (eg == 0) {
                float inv = 1.0f / fmaxf((float)cnt_n, 1.0f);
                float4 tv = *(const float4*)&T[(size_t)node * 16 + t4 * 4];
                float r0 = a0 * inv + tv.x;
                float r1 = a1 * inv + tv.y;
                float r2 = a2 * inv + tv.z;
                float r3 = a3 * inv + tv.w;
                if (t4 < 2) {
                    uint2 o;
                    o.x = f2bf(r0) | (f2bf(r1) << 16);
                    o.y = f2bf(r2) | (f2bf(r3) << 16);
                    *(uint2*)(pbf + (size_t)node * 4 + t4 * 2) = o;
                } else {
                    float4 o; o.x = r0; o.y = r1; o.z = r2; o.w = r3;
                    *(float4*)(q + (size_t)node * 8 + (t4 - 2) * 4) = o;
                }
            }
        }
    }

    // ---- grid barrier: release my writes, arrive, wait for all blocks ----
    __threadfence();              // each thread: device-scope release
    __syncthreads();              // all block writes fenced
    if (tid == 0) {
        atomicAdd(barrier, 1);
        while (atomicAdd(barrier, 0) < nbkt) { }
    }
    __syncthreads();

    // ---- Phase C: final (2 nodes/wave; 16 eg x 2 x uint2 per 16B row) ----
    {
        int half = lane >> 5;
        int eg   = (lane >> 1) & 15;  // 16 edge groups
        int t2   = lane & 1;          // uint2 slot
        const uint2* P2 = (const uint2*)pbf;

        #pragma unroll 1
        for (int it = 0; it < 8; ++it) {
            int nl = it * 32 + wave * 2 + half;
            int node = (b << NBKT_SHIFT) + nl;
            if (node >= nNodes) continue;
            int cnt_n = cntA[nl];
            int lo = loff[nl];

            float a0 = 0.f, a1 = 0.f, a2 = 0.f, a3 = 0.f;
            int id = (eg < cnt_n) ? (int)ss[lo + eg] : -1;
            for (int base = 0; base < cnt_n; base += 16) {
                int en = base + 16 + eg;
                int idn = (en < cnt_n) ? (int)ss[lo + en] : -1;
                if (id >= 0) {
                    uint2 r = P2[(size_t)id * 2 + t2];
                    a0 += __uint_as_float(r.x << 16);
                    a1 += __uint_as_float(r.x & 0xffff0000u);
                    a2 += __uint_as_float(r.y << 16);
                    a3 += __uint_as_float(r.y & 0xffff0000u);
                }
                id = idn;
            }
            a0 += __shfl_xor(a0, 2);  a1 += __shfl_xor(a1, 2);
            a2 += __shfl_xor(a2, 2);  a3 += __shfl_xor(a3, 2);
            a0 += __shfl_xor(a0, 4);  a1 += __shfl_xor(a1, 4);
            a2 += __shfl_xor(a2, 4);  a3 += __shfl_xor(a3, 4);
            a0 += __shfl_xor(a0, 8);  a1 += __shfl_xor(a1, 8);
            a2 += __shfl_xor(a2, 8);  a3 += __shfl_xor(a3, 8);
            a0 += __shfl_xor(a0, 16); a1 += __shfl_xor(a1, 16);
            a2 += __shfl_xor(a2, 16); a3 += __shfl_xor(a3, 16);

            if (eg == 0) {
                float inv = 1.0f / fmaxf((float)cnt_n, 1.0f);
                float4 qv = *(const float4*)&q[(size_t)node * 8 + t2 * 4];
                float4 o;
                o.x = a0 * inv + qv.x; o.y = a1 * inv + qv.y;
                o.z = a2 * inv + qv.z; o.w = a3 * inv + qv.w;
                *(float4*)(out + (size_t)node * 8 + t2 * 4) = o;
            }
        }
    }
}

static inline size_t align256(size_t v) { return (v + 255) & ~(size_t)255; }

extern "C" void kernel_launch(void* const* d_in, const int* in_sizes, int n_in,
                              void* d_out, int out_size, void* d_ws, size_t ws_size,
                              hipStream_t stream) {
    const float* embeds = (const float*)d_in[0];
    const int*   ei     = (const int*)d_in[1];
    const float* Wl1    = (const float*)d_in[2];
    const float* bl1    = (const float*)d_in[3];
    const float* Wr1    = (const float*)d_in[4];
    const float* Wl2    = (const float*)d_in[5];
    const float* bl2    = (const float*)d_in[6];
    const float* Wr2    = (const float*)d_in[7];

    const int N = in_sizes[0] / N_FEATS;           // 50000
    const int E = in_sizes[1] / 2;                 // 800000
    const int* src = ei;
    const int* dst = ei + E;

    const int NBKT = (N + 255) >> NBKT_SHIFT;      // 196 coarse buckets
    const int NB1  = (E + EPB - 1) / EPB;          // 196 split blocks
    const int NSTRIPS = (N + 63) / 64;             // 782 gemm strips

    // workspace layout
    char* ws = (char*)d_ws;
    size_t off = 0;
    int*            cursor  = (int*)(ws + off); off += align256((size_t)NBKT * sizeof(int));
    int*            barrier = (int*)(ws + off); off += align256(sizeof(int));
    unsigned short* Wc      = (unsigned short*)(ws + off); off += align256(64 * 32 * sizeof(unsigned short));
    float*          bvec    = (float*)(ws + off); off += align256(16 * sizeof(float));
    unsigned*       pairs   = (unsigned*)(ws + off); off += align256((size_t)NBKT * CAP * sizeof(unsigned));
    unsigned*       G       = (unsigned*)(ws + off); off += align256((size_t)N * 16 * sizeof(unsigned short));
    float*          T       = (float*)(ws + off); off += align256((size_t)N * 16 * sizeof(float));
    unsigned*       pbf     = (unsigned*)(ws + off); off += align256((size_t)N * 4 * sizeof(unsigned));
    float*          q       = (float*)(ws + off); off += align256((size_t)N * 8 * sizeof(float));
    (void)ws_size;

    // 1. weight combine + cursor/barrier zero (tiny kernel, NOT memset)
    k_init<<<1, 256, 0, stream>>>(Wl1, bl1, Wr1, Wl2, bl2, Wr2, Wc, bvec,
                                  cursor, barrier, NBKT);
    // 2. bucket split (CAP regions) || MFMA GEMM
    k_split_gemm<<<NB1 + NSTRIPS, 256, 0, stream>>>(
        src, dst, cursor, pairs, E, NBKT, NB1,
        embeds, Wc, bvec, (unsigned short*)G, T, N, NSTRIPS);
    // 3. fused sort + gather2 + grid-barrier + final
    k_fg_final<<<NBKT, 1024, 0, stream>>>(
        pairs, cursor, G, T, pbf, q, barrier, (float*)d_out, N, NBKT);
}

// Round 20
// 57.647 us; speedup vs baseline: 2.1773x; 2.1773x over previous
//
#include <hip/hip_runtime.h>
#include <hip/hip_bf16.h>
#include <cstddef>

#define N_FEATS 64
#define NBKT_SHIFT 8       // coarse bucket = dst >> 8 (256 nodes per bucket)
#define EPB 4096           // edges per split block
#define CAP 6144           // per-bucket region capacity (mean 4081, ~32 sigma)
// NOTE: requires N <= 65536 (src fits u16). Here N = 50000.

typedef __attribute__((ext_vector_type(8))) short bf16x8;
typedef __attribute__((ext_vector_type(4))) float f32x4;

// round-to-nearest-even f32 -> bf16 bits
__device__ __forceinline__ unsigned f2bf(float f) {
    unsigned x = __float_as_uint(f);
    return (x + 0x7fffu + ((x >> 16) & 1u)) >> 16;
}

// ---------------------------------------------------------------------------
// k_init (1 block): combined weights + bias vector + zero bucket cursors.
//   Wc[64][32] = [Wl1@Wl2 | Wl1@Wr2 | Wr1@Wl2 | Wr1@Wr2]  (bf16)
//   bvec[16]   = [bl1@Wl2 | bl1@Wr2 + bl2]                 (f32)
// (NOT a hipMemsetAsync: runtime fill kernel for tiny buffers costs ~40 us
//  per dispatch in this graph — measured round 16. Grid spin-barriers cost
//  ~80 us — measured round 19. Keep the 4-dispatch structure.)
// ---------------------------------------------------------------------------
__global__ __launch_bounds__(256) void k_init(
        const float* __restrict__ Wl1, const float* __restrict__ bl1,
        const float* __restrict__ Wr1, const float* __restrict__ Wl2,
        const float* __restrict__ bl2, const float* __restrict__ Wr2,
        unsigned short* __restrict__ Wc, float* __restrict__ bvec,
        int* __restrict__ cursor, int nbkt) {
    int tid = threadIdx.x;
    int k = tid & 63, jg = tid >> 6;
    const float* W1 = (jg < 2) ? Wl1 : Wr1;
    const float* W2 = (jg & 1) ? Wr2 : Wl2;
    float acc[8] = {0.f,0.f,0.f,0.f,0.f,0.f,0.f,0.f};
    for (int m = 0; m < 64; ++m) {
        float w1 = W1[k * 64 + m];
        #pragma unroll
        for (int jj = 0; jj < 8; ++jj) acc[jj] += w1 * W2[m * 8 + jj];
    }
    #pragma unroll
    for (int jj = 0; jj < 8; ++jj)
        Wc[k * 32 + jg * 8 + jj] = (unsigned short)f2bf(acc[jj]);
    if (tid < 16) {
        const float* W2b = (tid < 8) ? Wl2 : Wr2;
        float a = 0.f;
        for (int m = 0; m < 64; ++m) a += bl1[m] * W2b[m * 8 + (tid & 7)];
        if (tid >= 8) a += bl2[tid - 8];
        bvec[tid] = a;
    }
    if (tid < nbkt) cursor[tid] = 0;
}

// ---------------------------------------------------------------------------
// Fused dispatch: blocks < nb1 split edges into fixed-CAP bucket regions
// (int4 edge loads -> LDS pack -> count, one global reservation atomic per
// bucket per block). Blocks >= nb1 run the MFMA GEMM Y = X@Wc -> G, T.
// ---------------------------------------------------------------------------
__global__ __launch_bounds__(256) void k_split_gemm(
        const int* __restrict__ src, const int* __restrict__ dst,
        int* __restrict__ cursor, unsigned* __restrict__ pairs,
        int nEdges, int nbkt, int nb1,
        const float* __restrict__ x,
        const unsigned short* __restrict__ Wc,
        const float* __restrict__ bvec,
        unsigned short* __restrict__ G,   // bf16 [N][16] = [s|s']
        float* __restrict__ T,            // f32  [N][16] = [t|t'] (+bias)
        int nNodes, int nStrips) {
    __shared__ unsigned spr[EPB];
    __shared__ int lh[256];
    __shared__ int lcur[256];
    int tid = threadIdx.x, b = blockIdx.x;

    if (b < nb1) {
        lh[tid] = 0;
        __syncthreads();
        int base = b * EPB;
        int m = nEdges - base; if (m > EPB) m = EPB;
        int m4 = m >> 2;
        const int4* dst4 = (const int4*)(dst + base);
        const int4* src4 = (const int4*)(src + base);
        for (int j = tid; j < m4; j += 256) {
            int4 d4 = dst4[j];
            int4 s4 = src4[j];
            uint4 p4;
            p4.x = ((unsigned)s4.x << 16) | (unsigned)d4.x;
            p4.y = ((unsigned)s4.y << 16) | (unsigned)d4.y;
            p4.z = ((unsigned)s4.z << 16) | (unsigned)d4.z;
            p4.w = ((unsigned)s4.w << 16) | (unsigned)d4.w;
            ((uint4*)spr)[j] = p4;
            atomicAdd(&lh[(unsigned)d4.x >> NBKT_SHIFT], 1);
            atomicAdd(&lh[(unsigned)d4.y >> NBKT_SHIFT], 1);
            atomicAdd(&lh[(unsigned)d4.z >> NBKT_SHIFT], 1);
            atomicAdd(&lh[(unsigned)d4.w >> NBKT_SHIFT], 1);
        }
        for (int j = m4 * 4 + tid; j < m; j += 256) {
            unsigned d = (unsigned)dst[base + j];
            spr[j] = ((unsigned)src[base + j] << 16) | d;
            atomicAdd(&lh[d >> NBKT_SHIFT], 1);
        }
        __syncthreads();
        if (tid < nbkt) lcur[tid] = atomicAdd(&cursor[tid], lh[tid]);
        __syncthreads();
        for (int j = tid; j < m; j += 256) {
            unsigned pr = spr[j];
            unsigned d = pr & 0xffffu;
            int bkt = d >> NBKT_SHIFT;
            int pos = atomicAdd(&lcur[bkt], 1);
            if (pos < CAP)
                pairs[(size_t)bkt * CAP + pos] = ((pr >> 16) << 8) | (d & 255u);
        }
        return;
    }

    // ---- MFMA GEMM ----
    int w  = tid >> 6;
    int l  = tid & 63;
    int fc = l & 15;
    int kg = l >> 4;
    bf16x8 bf[2][2];
    #pragma unroll
    for (int ct = 0; ct < 2; ++ct)
        #pragma unroll
        for (int kh = 0; kh < 2; ++kh)
            #pragma unroll
            for (int i = 0; i < 8; ++i) {
                int k = kh * 32 + kg * 8 + i;
                bf[ct][kh][i] = (short)Wc[k * 32 + ct * 16 + fc];
            }
    float bias = bvec[fc];

    for (int strip = b - nb1; strip < nStrips; strip += gridDim.x - nb1) {
        int node0 = strip * 64;
        int arow = node0 + w * 16 + fc;
        int ar = (arow < nNodes) ? arow : (nNodes - 1);
        const float* xp = x + (size_t)ar * 64 + kg * 8;
        float4 xa = *(const float4*)(xp);
        float4 xb = *(const float4*)(xp + 4);
        float4 xc = *(const float4*)(xp + 32);
        float4 xd = *(const float4*)(xp + 36);
        bf16x8 a0, a1;
        a0[0]=(short)f2bf(xa.x); a0[1]=(short)f2bf(xa.y);
        a0[2]=(short)f2bf(xa.z); a0[3]=(short)f2bf(xa.w);
        a0[4]=(short)f2bf(xb.x); a0[5]=(short)f2bf(xb.y);
        a0[6]=(short)f2bf(xb.z); a0[7]=(short)f2bf(xb.w);
        a1[0]=(short)f2bf(xc.x); a1[1]=(short)f2bf(xc.y);
        a1[2]=(short)f2bf(xc.z); a1[3]=(short)f2bf(xc.w);
        a1[4]=(short)f2bf(xd.x); a1[5]=(short)f2bf(xd.y);
        a1[6]=(short)f2bf(xd.z); a1[7]=(short)f2bf(xd.w);

        f32x4 d0 = {0.f, 0.f, 0.f, 0.f};
        f32x4 d1 = {0.f, 0.f, 0.f, 0.f};
        d0 = __builtin_amdgcn_mfma_f32_16x16x32_bf16(a0, bf[0][0], d0, 0, 0, 0);
        d0 = __builtin_amdgcn_mfma_f32_16x16x32_bf16(a1, bf[0][1], d0, 0, 0, 0);
        d1 = __builtin_amdgcn_mfma_f32_16x16x32_bf16(a0, bf[1][0], d1, 0, 0, 0);
        d1 = __builtin_amdgcn_mfma_f32_16x16x32_bf16(a1, bf[1][1], d1, 0, 0, 0);

        #pragma unroll
        for (int r = 0; r < 4; ++r) {
            int node = node0 + w * 16 + kg * 4 + r;
            if (node < nNodes) {
                G[(size_t)node * 16 + fc] = (unsigned short)f2bf(d0[r]);
                T[(size_t)node * 16 + fc] = d1[r] + bias;
            }
        }
    }
}

// ---------------------------------------------------------------------------
// Fused sort + layer-1 gather: one 1024-thread block per bucket.
// Phase A: single global read of the bucket's pairs (staged to LDS spr),
// counting sort by dst&255 -> LDS ss[] (+ global sorted_src for k_final).
// Phase B: 16 waves x 2 nodes: p = mean-gather(s)+t (bf16), q = .. (f32).
// ---------------------------------------------------------------------------
__global__ __launch_bounds__(1024) void k_fsort_gather2(
        const unsigned* __restrict__ pairs,
        const int* __restrict__ cursor,
        const unsigned* __restrict__ G,     // [N][8] uints (16 bf16)
        const float* __restrict__ T,        // [N][16]
        int* __restrict__ counts,
        int* __restrict__ offsets,
        unsigned short* __restrict__ sorted_src,
        unsigned* __restrict__ pbf,         // [N][4] uints (8 bf16)
        float* __restrict__ q,              // [N][8]
        int nNodes, int nbkt) {
    __shared__ unsigned spr[CAP];          // 24.6 KB staged pairs
    __shared__ unsigned short ss[CAP];     // 12.3 KB sorted src
    __shared__ int cntA[256];
    __shared__ int scanbuf[256];
    __shared__ int loff[256];
    __shared__ int cur[256];
    int tid = threadIdx.x, b = blockIdx.x;
    int bStart = b * CAP;
    int m = cursor[b]; if (m > CAP) m = CAP;

    // ---- Phase A: counting sort (single global pass over pairs) ----
    if (tid < 256) cntA[tid] = 0;
    __syncthreads();
    for (int e = tid; e < m; e += 1024) {
        unsigned pr = pairs[bStart + e];
        spr[e] = pr;
        atomicAdd(&cntA[pr & 255u], 1);
    }
    __syncthreads();
    int v = 0;
    if (tid < 256) { v = cntA[tid]; scanbuf[tid] = v; }
    __syncthreads();
    for (int d = 1; d < 256; d <<= 1) {
        int t = (tid < 256 && tid >= d) ? scanbuf[tid - d] : 0;
        __syncthreads();
        if (tid < 256) scanbuf[tid] += t;
        __syncthreads();
    }
    if (tid < 256) {
        int excl = scanbuf[tid] - v;
        loff[tid] = excl;
        cur[tid] = excl;
        int node = (b << NBKT_SHIFT) + tid;
        if (node < nNodes) { counts[node] = v; offsets[node] = bStart + excl; }
    }
    __syncthreads();
    for (int e = tid; e < m; e += 1024) {
        unsigned pr = spr[e];
        int pos = atomicAdd(&cur[pr & 255u], 1);
        unsigned short sv = (unsigned short)(pr >> 8);
        ss[pos] = sv;
        sorted_src[bStart + pos] = sv;   // for k_final
    }
    __syncthreads();

    // ---- Phase B: gather2 (2 nodes/wave, 16 waves -> 32 nodes/iter) ----
    int wave = tid >> 6, lane = tid & 63;
    int half = lane >> 5;
    int eg   = (lane >> 2) & 7;   // 8 edge groups
    int t4   = lane & 3;          // uint2 slot (8B)
    const uint2* G2 = (const uint2*)G;

    #pragma unroll 1
    for (int it = 0; it < 8; ++it) {
        int nl = it * 32 + wave * 2 + half;
        int node = (b << NBKT_SHIFT) + nl;
        if (node >= nNodes) continue;
        int cnt_n = cntA[nl];
        int lo = loff[nl];

        float a0 = 0.f, a1 = 0.f, a2 = 0.f, a3 = 0.f;
        int id = (eg < cnt_n) ? (int)ss[lo + eg] : -1;
        for (int base = 0; base < cnt_n; base += 8) {
            int en = base + 8 + eg;
            int idn = (en < cnt_n) ? (int)ss[lo + en] : -1;
            if (id >= 0) {
                uint2 r = G2[(size_t)id * 4 + t4];
                a0 += __uint_as_float(r.x << 16);
                a1 += __uint_as_float(r.x & 0xffff0000u);
                a2 += __uint_as_float(r.y << 16);
                a3 += __uint_as_float(r.y & 0xffff0000u);
            }
            id = idn;
        }
        a0 += __shfl_xor(a0, 4);  a1 += __shfl_xor(a1, 4);
        a2 += __shfl_xor(a2, 4);  a3 += __shfl_xor(a3, 4);
        a0 += __shfl_xor(a0, 8);  a1 += __shfl_xor(a1, 8);
        a2 += __shfl_xor(a2, 8);  a3 += __shfl_xor(a3, 8);
        a0 += __shfl_xor(a0, 16); a1 += __shfl_xor(a1, 16);
        a2 += __shfl_xor(a2, 16); a3 += __shfl_xor(a3, 16);

        if (eg == 0) {
            float inv = 1.0f / fmaxf((float)cnt_n, 1.0f);
            float4 tv = *(const float4*)&T[(size_t)node * 16 + t4 * 4];
            float r0 = a0 * inv + tv.x;
            float r1 = a1 * inv + tv.y;
            float r2 = a2 * inv + tv.z;
            float r3 = a3 * inv + tv.w;
            if (t4 < 2) {
                uint2 o;
                o.x = f2bf(r0) | (f2bf(r1) << 16);
                o.y = f2bf(r2) | (f2bf(r3) << 16);
                *(uint2*)(pbf + (size_t)node * 4 + t4 * 2) = o;
            } else {
                float4 o; o.x = r0; o.y = r1; o.z = r2; o.w = r3;
                *(float4*)(q + (size_t)node * 8 + (t4 - 2) * 4) = o;
            }
        }
    }
}

// ---------------------------------------------------------------------------
// out = mean-gather(p) + q.  4 nodes/wave: quarter = lane>>4; 8 edge-groups
// x 2 lanes x uint2 (8B) per 16B pbf-row. Reduce shfl_xor 2/4/8 (within the
// 16-lane quarter).
// ---------------------------------------------------------------------------
__global__ __launch_bounds__(256) void k_final(
        const unsigned* __restrict__ pbf,   // [N][4] uints (8 bf16)
        const float* __restrict__ q,        // [N][8]
        const int* __restrict__ counts,
        const int* __restrict__ offsets,
        const unsigned short* __restrict__ ss,
        float* __restrict__ out,
        int nNodes) {
    int tid  = threadIdx.x;
    int wave = tid >> 6, lane = tid & 63;
    int quarter = lane >> 4;      // node within wave, 0..3
    int eg   = (lane >> 1) & 7;   // 8 edge groups
    int t2   = lane & 1;          // uint2 slot: values t2*4 .. t2*4+3
    int node = blockIdx.x * 16 + wave * 4 + quarter;
    if (node >= nNodes) return;
    int cnt = counts[node], off = offsets[node];
    const uint2* P2 = (const uint2*)pbf;    // 2 x uint2 per row

    float a0 = 0.f, a1 = 0.f, a2 = 0.f, a3 = 0.f;
    int id = (eg < cnt) ? (int)ss[off + eg] : -1;
    for (int base = 0; base < cnt; base += 8) {
        int en = base + 8 + eg;
        int idn = (en < cnt) ? (int)ss[off + en] : -1;
        if (id >= 0) {
            uint2 r = P2[(size_t)id * 2 + t2];
            a0 += __uint_as_float(r.x << 16);
            a1 += __uint_as_float(r.x & 0xffff0000u);
            a2 += __uint_as_float(r.y << 16);
            a3 += __uint_as_float(r.y & 0xffff0000u);
        }
        id = idn;
    }
    a0 += __shfl_xor(a0, 2);  a1 += __shfl_xor(a1, 2);
    a2 += __shfl_xor(a2, 2);  a3 += __shfl_xor(a3, 2);
    a0 += __shfl_xor(a0, 4);  a1 += __shfl_xor(a1, 4);
    a2 += __shfl_xor(a2, 4);  a3 += __shfl_xor(a3, 4);
    a0 += __shfl_xor(a0, 8);  a1 += __shfl_xor(a1, 8);
    a2 += __shfl_xor(a2, 8);  a3 += __shfl_xor(a3, 8);

    if (eg == 0) {
        float inv = 1.0f / fmaxf((float)cnt, 1.0f);
        float4 qv = *(const float4*)&q[(size_t)node * 8 + t2 * 4];
        float4 o;
        o.x = a0 * inv + qv.x; o.y = a1 * inv + qv.y;
        o.z = a2 * inv + qv.z; o.w = a3 * inv + qv.w;
        *(float4*)(out + (size_t)node * 8 + t2 * 4) = o;
    }
}

static inline size_t align256(size_t v) { return (v + 255) & ~(size_t)255; }

extern "C" void kernel_launch(void* const* d_in, const int* in_sizes, int n_in,
                              void* d_out, int out_size, void* d_ws, size_t ws_size,
                              hipStream_t stream) {
    const float* embeds = (const float*)d_in[0];
    const int*   ei     = (const int*)d_in[1];
    const float* Wl1    = (const float*)d_in[2];
    const float* bl1    = (const float*)d_in[3];
    const float* Wr1    = (const float*)d_in[4];
    const float* Wl2    = (const float*)d_in[5];
    const float* bl2    = (const float*)d_in[6];
    const float* Wr2    = (const float*)d_in[7];

    const int N = in_sizes[0] / N_FEATS;           // 50000
    const int E = in_sizes[1] / 2;                 // 800000
    const int* src = ei;
    const int* dst = ei + E;

    const int NBKT = (N + 255) >> NBKT_SHIFT;      // 196 coarse buckets
    const int NB1  = (E + EPB - 1) / EPB;          // 196 split blocks
    const int NSTRIPS = (N + 63) / 64;             // 782 gemm strips

    // workspace layout
    char* ws = (char*)d_ws;
    size_t off = 0;
    int*            cursor     = (int*)(ws + off); off += align256((size_t)NBKT * sizeof(int));
    int*            counts     = (int*)(ws + off); off += align256((size_t)N * sizeof(int));
    int*            offsets    = (int*)(ws + off); off += align256((size_t)N * sizeof(int));
    unsigned short* Wc         = (unsigned short*)(ws + off); off += align256(64 * 32 * sizeof(unsigned short));
    float*          bvec       = (float*)(ws + off); off += align256(16 * sizeof(float));
    unsigned*       pairs      = (unsigned*)(ws + off); off += align256((size_t)NBKT * CAP * sizeof(unsigned));
    unsigned short* sorted_src = (unsigned short*)(ws + off); off += align256((size_t)NBKT * CAP * sizeof(unsigned short));
    unsigned*       G          = (unsigned*)(ws + off); off += align256((size_t)N * 16 * sizeof(unsigned short));
    float*          T          = (float*)(ws + off); off += align256((size_t)N * 16 * sizeof(float));
    unsigned*       pbf        = (unsigned*)(ws + off); off += align256((size_t)N * 4 * sizeof(unsigned));
    float*          q          = (float*)(ws + off); off += align256((size_t)N * 8 * sizeof(float));
    (void)ws_size;

    // 1. weight combine + cursor zero (tiny kernel, NOT memset)
    k_init<<<1, 256, 0, stream>>>(Wl1, bl1, Wr1, Wl2, bl2, Wr2, Wc, bvec,
                                  cursor, NBKT);
    // 2. bucket split (CAP regions) || MFMA GEMM
    k_split_gemm<<<NB1 + NSTRIPS, 256, 0, stream>>>(
        src, dst, cursor, pairs, E, NBKT, NB1,
        embeds, Wc, bvec, (unsigned short*)G, T, N, NSTRIPS);
    // 3. fused per-bucket sort + layer-1 gather -> pbf, q (+CSR for final)
    k_fsort_gather2<<<NBKT, 1024, 0, stream>>>(
        pairs, cursor, G, T, counts, offsets, sorted_src, pbf, q, N, NBKT);
    // 4. out = mean-gather(p) + q   (4 nodes/wave)
    k_final<<<(N + 15) / 16, 256, 0, stream>>>(pbf, q, counts, offsets,
                                               sorted_src, (float*)d_out, N);
}

// Round 21
// 52.649 us; speedup vs baseline: 2.3839x; 1.0949x over previous
//
#include <hip/hip_runtime.h>
#include <hip/hip_bf16.h>
#include <cstddef>

#define N_FEATS 64
#define NBKT_SHIFT 7       // coarse bucket = dst >> 7 (128 nodes per bucket)
#define NPBKT 128          // nodes per bucket
#define EPB 4096           // edges per split block
#define CAP 2560           // per-bucket region capacity (mean 2048, ~11 sigma)
// NOTE: requires N <= 65536 (src fits u16). Here N = 50000.

typedef __attribute__((ext_vector_type(8))) short bf16x8;
typedef __attribute__((ext_vector_type(4))) float f32x4;

// round-to-nearest-even f32 -> bf16 bits
__device__ __forceinline__ unsigned f2bf(float f) {
    unsigned x = __float_as_uint(f);
    return (x + 0x7fffu + ((x >> 16) & 1u)) >> 16;
}

// ---------------------------------------------------------------------------
// k_init (1 block): combined weights + bias vector + zero bucket cursors.
//   Wc[64][32] = [Wl1@Wl2 | Wl1@Wr2 | Wr1@Wl2 | Wr1@Wr2]  (bf16)
//   bvec[16]   = [bl1@Wl2 | bl1@Wr2 + bl2]                 (f32)
// (NOT a hipMemsetAsync: runtime fill kernel for tiny buffers costs ~40 us
//  per dispatch in this graph — measured round 16. Grid spin-barriers cost
//  ~80 us — measured round 19. Keep the 4-dispatch structure.)
// ---------------------------------------------------------------------------
__global__ __launch_bounds__(256) void k_init(
        const float* __restrict__ Wl1, const float* __restrict__ bl1,
        const float* __restrict__ Wr1, const float* __restrict__ Wl2,
        const float* __restrict__ bl2, const float* __restrict__ Wr2,
        unsigned short* __restrict__ Wc, float* __restrict__ bvec,
        int* __restrict__ cursor, int nbkt) {
    int tid = threadIdx.x;
    int k = tid & 63, jg = tid >> 6;
    const float* W1 = (jg < 2) ? Wl1 : Wr1;
    const float* W2 = (jg & 1) ? Wr2 : Wl2;
    float acc[8] = {0.f,0.f,0.f,0.f,0.f,0.f,0.f,0.f};
    for (int m = 0; m < 64; ++m) {
        float w1 = W1[k * 64 + m];
        #pragma unroll
        for (int jj = 0; jj < 8; ++jj) acc[jj] += w1 * W2[m * 8 + jj];
    }
    #pragma unroll
    for (int jj = 0; jj < 8; ++jj)
        Wc[k * 32 + jg * 8 + jj] = (unsigned short)f2bf(acc[jj]);
    if (tid < 16) {
        const float* W2b = (tid < 8) ? Wl2 : Wr2;
        float a = 0.f;
        for (int m = 0; m < 64; ++m) a += bl1[m] * W2b[m * 8 + (tid & 7)];
        if (tid >= 8) a += bl2[tid - 8];
        bvec[tid] = a;
    }
    for (int i = tid; i < nbkt; i += 256) cursor[i] = 0;
}

// ---------------------------------------------------------------------------
// Fused dispatch: blocks < nb1 split edges into fixed-CAP bucket regions
// (int4 edge loads -> LDS pack -> count, one global reservation atomic per
// bucket per block). Blocks >= nb1 run the MFMA GEMM Y = X@Wc -> G, T.
// ---------------------------------------------------------------------------
__global__ __launch_bounds__(256) void k_split_gemm(
        const int* __restrict__ src, const int* __restrict__ dst,
        int* __restrict__ cursor, unsigned* __restrict__ pairs,
        int nEdges, int nbkt, int nb1,
        const float* __restrict__ x,
        const unsigned short* __restrict__ Wc,
        const float* __restrict__ bvec,
        unsigned short* __restrict__ G,   // bf16 [N][16] = [s|s']
        float* __restrict__ T,            // f32  [N][16] = [t|t'] (+bias)
        int nNodes, int nStrips) {
    __shared__ unsigned spr[EPB];
    __shared__ int lh[512];
    __shared__ int lcur[512];
    int tid = threadIdx.x, b = blockIdx.x;

    if (b < nb1) {
        for (int i = tid; i < nbkt; i += 256) lh[i] = 0;
        __syncthreads();
        int base = b * EPB;
        int m = nEdges - base; if (m > EPB) m = EPB;
        int m4 = m >> 2;
        const int4* dst4 = (const int4*)(dst + base);
        const int4* src4 = (const int4*)(src + base);
        for (int j = tid; j < m4; j += 256) {
            int4 d4 = dst4[j];
            int4 s4 = src4[j];
            uint4 p4;
            p4.x = ((unsigned)s4.x << 16) | (unsigned)d4.x;
            p4.y = ((unsigned)s4.y << 16) | (unsigned)d4.y;
            p4.z = ((unsigned)s4.z << 16) | (unsigned)d4.z;
            p4.w = ((unsigned)s4.w << 16) | (unsigned)d4.w;
            ((uint4*)spr)[j] = p4;
            atomicAdd(&lh[(unsigned)d4.x >> NBKT_SHIFT], 1);
            atomicAdd(&lh[(unsigned)d4.y >> NBKT_SHIFT], 1);
            atomicAdd(&lh[(unsigned)d4.z >> NBKT_SHIFT], 1);
            atomicAdd(&lh[(unsigned)d4.w >> NBKT_SHIFT], 1);
        }
        for (int j = m4 * 4 + tid; j < m; j += 256) {
            unsigned d = (unsigned)dst[base + j];
            spr[j] = ((unsigned)src[base + j] << 16) | d;
            atomicAdd(&lh[d >> NBKT_SHIFT], 1);
        }
        __syncthreads();
        for (int i = tid; i < nbkt; i += 256)
            lcur[i] = atomicAdd(&cursor[i], lh[i]);
        __syncthreads();
        for (int j = tid; j < m; j += 256) {
            unsigned pr = spr[j];
            unsigned d = pr & 0xffffu;
            int bkt = d >> NBKT_SHIFT;
            int pos = atomicAdd(&lcur[bkt], 1);
            if (pos < CAP)
                pairs[(size_t)bkt * CAP + pos] = ((pr >> 16) << 8) | (d & 127u);
        }
        return;
    }

    // ---- MFMA GEMM ----
    int w  = tid >> 6;
    int l  = tid & 63;
    int fc = l & 15;
    int kg = l >> 4;
    bf16x8 bf[2][2];
    #pragma unroll
    for (int ct = 0; ct < 2; ++ct)
        #pragma unroll
        for (int kh = 0; kh < 2; ++kh)
            #pragma unroll
            for (int i = 0; i < 8; ++i) {
                int k = kh * 32 + kg * 8 + i;
                bf[ct][kh][i] = (short)Wc[k * 32 + ct * 16 + fc];
            }
    float bias = bvec[fc];

    for (int strip = b - nb1; strip < nStrips; strip += gridDim.x - nb1) {
        int node0 = strip * 64;
        int arow = node0 + w * 16 + fc;
        int ar = (arow < nNodes) ? arow : (nNodes - 1);
        const float* xp = x + (size_t)ar * 64 + kg * 8;
        float4 xa = *(const float4*)(xp);
        float4 xb = *(const float4*)(xp + 4);
        float4 xc = *(const float4*)(xp + 32);
        float4 xd = *(const float4*)(xp + 36);
        bf16x8 a0, a1;
        a0[0]=(short)f2bf(xa.x); a0[1]=(short)f2bf(xa.y);
        a0[2]=(short)f2bf(xa.z); a0[3]=(short)f2bf(xa.w);
        a0[4]=(short)f2bf(xb.x); a0[5]=(short)f2bf(xb.y);
        a0[6]=(short)f2bf(xb.z); a0[7]=(short)f2bf(xb.w);
        a1[0]=(short)f2bf(xc.x); a1[1]=(short)f2bf(xc.y);
        a1[2]=(short)f2bf(xc.z); a1[3]=(short)f2bf(xc.w);
        a1[4]=(short)f2bf(xd.x); a1[5]=(short)f2bf(xd.y);
        a1[6]=(short)f2bf(xd.z); a1[7]=(short)f2bf(xd.w);

        f32x4 d0 = {0.f, 0.f, 0.f, 0.f};
        f32x4 d1 = {0.f, 0.f, 0.f, 0.f};
        d0 = __builtin_amdgcn_mfma_f32_16x16x32_bf16(a0, bf[0][0], d0, 0, 0, 0);
        d0 = __builtin_amdgcn_mfma_f32_16x16x32_bf16(a1, bf[0][1], d0, 0, 0, 0);
        d1 = __builtin_amdgcn_mfma_f32_16x16x32_bf16(a0, bf[1][0], d1, 0, 0, 0);
        d1 = __builtin_amdgcn_mfma_f32_16x16x32_bf16(a1, bf[1][1], d1, 0, 0, 0);

        #pragma unroll
        for (int r = 0; r < 4; ++r) {
            int node = node0 + w * 16 + kg * 4 + r;
            if (node < nNodes) {
                G[(size_t)node * 16 + fc] = (unsigned short)f2bf(d0[r]);
                T[(size_t)node * 16 + fc] = d1[r] + bias;
            }
        }
    }
}

// ---------------------------------------------------------------------------
// Fused sort + layer-1 gather: one 1024-thread block per bucket (391 blocks,
// ~18 KB LDS -> 2 blocks/CU co-resident, full-chip coverage).
// Phase A: single global read of pairs (staged to LDS), 7-bit counting sort
// -> LDS ss[] (+ global sorted_src for k_final) + counts/offsets.
// Phase B: 16 waves x 2 nodes x 4 iters: p = mean-gather(s)+t (bf16),
// q = mean-gather(s')+t' (f32); edge lists from LDS, G rows from global.
// ---------------------------------------------------------------------------
__global__ __launch_bounds__(1024) void k_fsort_gather2(
        const unsigned* __restrict__ pairs,
        const int* __restrict__ cursor,
        const unsigned* __restrict__ G,     // [N][8] uints (16 bf16)
        const float* __restrict__ T,        // [N][16]
        int* __restrict__ counts,
        int* __restrict__ offsets,
        unsigned short* __restrict__ sorted_src,
        unsigned* __restrict__ pbf,         // [N][4] uints (8 bf16)
        float* __restrict__ q,              // [N][8]
        int nNodes, int nbkt) {
    __shared__ unsigned spr[CAP];          // 10.2 KB staged pairs
    __shared__ unsigned short ss[CAP];     // 5.1 KB sorted src
    __shared__ int cntA[NPBKT];
    __shared__ int scanbuf[NPBKT];
    __shared__ int loff[NPBKT];
    __shared__ int cur[NPBKT];
    int tid = threadIdx.x, b = blockIdx.x;
    int bStart = b * CAP;
    int m = cursor[b]; if (m > CAP) m = CAP;

    // ---- Phase A: counting sort (single global pass over pairs) ----
    if (tid < NPBKT) cntA[tid] = 0;
    __syncthreads();
    for (int e = tid; e < m; e += 1024) {
        unsigned pr = pairs[bStart + e];
        spr[e] = pr;
        atomicAdd(&cntA[pr & 127u], 1);
    }
    __syncthreads();
    int v = 0;
    if (tid < NPBKT) { v = cntA[tid]; scanbuf[tid] = v; }
    __syncthreads();
    for (int d = 1; d < NPBKT; d <<= 1) {
        int t = (tid < NPBKT && tid >= d) ? scanbuf[tid - d] : 0;
        __syncthreads();
        if (tid < NPBKT) scanbuf[tid] += t;
        __syncthreads();
    }
    if (tid < NPBKT) {
        int excl = scanbuf[tid] - v;
        loff[tid] = excl;
        cur[tid] = excl;
        int node = (b << NBKT_SHIFT) + tid;
        if (node < nNodes) { counts[node] = v; offsets[node] = bStart + excl; }
    }
    __syncthreads();
    for (int e = tid; e < m; e += 1024) {
        unsigned pr = spr[e];
        int pos = atomicAdd(&cur[pr & 127u], 1);
        unsigned short sv = (unsigned short)(pr >> 8);
        ss[pos] = sv;
        sorted_src[bStart + pos] = sv;   // for k_final
    }
    __syncthreads();

    // ---- Phase B: gather2 (2 nodes/wave, 16 waves -> 32 nodes/iter) ----
    int wave = tid >> 6, lane = tid & 63;
    int half = lane >> 5;
    int eg   = (lane >> 2) & 7;   // 8 edge groups
    int t4   = lane & 3;          // uint2 slot (8B)
    const uint2* G2 = (const uint2*)G;

    #pragma unroll 1
    for (int it = 0; it < NPBKT / 32; ++it) {
        int nl = it * 32 + wave * 2 + half;
        int node = (b << NBKT_SHIFT) + nl;
        if (node >= nNodes) continue;
        int cnt_n = cntA[nl];
        int lo = loff[nl];

        float a0 = 0.f, a1 = 0.f, a2 = 0.f, a3 = 0.f;
        int id = (eg < cnt_n) ? (int)ss[lo + eg] : -1;
        for (int base = 0; base < cnt_n; base += 8) {
            int en = base + 8 + eg;
            int idn = (en < cnt_n) ? (int)ss[lo + en] : -1;
            if (id >= 0) {
                uint2 r = G2[(size_t)id * 4 + t4];
                a0 += __uint_as_float(r.x << 16);
                a1 += __uint_as_float(r.x & 0xffff0000u);
                a2 += __uint_as_float(r.y << 16);
                a3 += __uint_as_float(r.y & 0xffff0000u);
            }
            id = idn;
        }
        a0 += __shfl_xor(a0, 4);  a1 += __shfl_xor(a1, 4);
        a2 += __shfl_xor(a2, 4);  a3 += __shfl_xor(a3, 4);
        a0 += __shfl_xor(a0, 8);  a1 += __shfl_xor(a1, 8);
        a2 += __shfl_xor(a2, 8);  a3 += __shfl_xor(a3, 8);
        a0 += __shfl_xor(a0, 16); a1 += __shfl_xor(a1, 16);
        a2 += __shfl_xor(a2, 16); a3 += __shfl_xor(a3, 16);

        if (eg == 0) {
            float inv = 1.0f / fmaxf((float)cnt_n, 1.0f);
            float4 tv = *(const float4*)&T[(size_t)node * 16 + t4 * 4];
            float r0 = a0 * inv + tv.x;
            float r1 = a1 * inv + tv.y;
            float r2 = a2 * inv + tv.z;
            float r3 = a3 * inv + tv.w;
            if (t4 < 2) {
                uint2 o;
                o.x = f2bf(r0) | (f2bf(r1) << 16);
                o.y = f2bf(r2) | (f2bf(r3) << 16);
                *(uint2*)(pbf + (size_t)node * 4 + t4 * 2) = o;
            } else {
                float4 o; o.x = r0; o.y = r1; o.z = r2; o.w = r3;
                *(float4*)(q + (size_t)node * 8 + (t4 - 2) * 4) = o;
            }
        }
    }
}

// ---------------------------------------------------------------------------
// out = mean-gather(p) + q.  4 nodes/wave: quarter = lane>>4; 8 edge-groups
// x 2 lanes x uint2 (8B) per 16B pbf-row. Reduce shfl_xor 2/4/8 (within the
// 16-lane quarter).
// ---------------------------------------------------------------------------
__global__ __launch_bounds__(256) void k_final(
        const unsigned* __restrict__ pbf,   // [N][4] uints (8 bf16)
        const float* __restrict__ q,        // [N][8]
        const int* __restrict__ counts,
        const int* __restrict__ offsets,
        const unsigned short* __restrict__ ss,
        float* __restrict__ out,
        int nNodes) {
    int tid  = threadIdx.x;
    int wave = tid >> 6, lane = tid & 63;
    int quarter = lane >> 4;      // node within wave, 0..3
    int eg   = (lane >> 1) & 7;   // 8 edge groups
    int t2   = lane & 1;          // uint2 slot: values t2*4 .. t2*4+3
    int node = blockIdx.x * 16 + wave * 4 + quarter;
    if (node >= nNodes) return;
    int cnt = counts[node], off = offsets[node];
    const uint2* P2 = (const uint2*)pbf;    // 2 x uint2 per row

    float a0 = 0.f, a1 = 0.f, a2 = 0.f, a3 = 0.f;
    int id = (eg < cnt) ? (int)ss[off + eg] : -1;
    for (int base = 0; base < cnt; base += 8) {
        int en = base + 8 + eg;
        int idn = (en < cnt) ? (int)ss[off + en] : -1;
        if (id >= 0) {
            uint2 r = P2[(size_t)id * 2 + t2];
            a0 += __uint_as_float(r.x << 16);
            a1 += __uint_as_float(r.x & 0xffff0000u);
            a2 += __uint_as_float(r.y << 16);
            a3 += __uint_as_float(r.y & 0xffff0000u);
        }
        id = idn;
    }
    a0 += __shfl_xor(a0, 2);  a1 += __shfl_xor(a1, 2);
    a2 += __shfl_xor(a2, 2);  a3 += __shfl_xor(a3, 2);
    a0 += __shfl_xor(a0, 4);  a1 += __shfl_xor(a1, 4);
    a2 += __shfl_xor(a2, 4);  a3 += __shfl_xor(a3, 4);
    a0 += __shfl_xor(a0, 8);  a1 += __shfl_xor(a1, 8);
    a2 += __shfl_xor(a2, 8);  a3 += __shfl_xor(a3, 8);

    if (eg == 0) {
        float inv = 1.0f / fmaxf((float)cnt, 1.0f);
        float4 qv = *(const float4*)&q[(size_t)node * 8 + t2 * 4];
        float4 o;
        o.x = a0 * inv + qv.x; o.y = a1 * inv + qv.y;
        o.z = a2 * inv + qv.z; o.w = a3 * inv + qv.w;
        *(float4*)(out + (size_t)node * 8 + t2 * 4) = o;
    }
}

static inline size_t align256(size_t v) { return (v + 255) & ~(size_t)255; }

extern "C" void kernel_launch(void* const* d_in, const int* in_sizes, int n_in,
                              void* d_out, int out_size, void* d_ws, size_t ws_size,
                              hipStream_t stream) {
    const float* embeds = (const float*)d_in[0];
    const int*   ei     = (const int*)d_in[1];
    const float* Wl1    = (const float*)d_in[2];
    const float* bl1    = (const float*)d_in[3];
    const float* Wr1    = (const float*)d_in[4];
    const float* Wl2    = (const float*)d_in[5];
    const float* bl2    = (const float*)d_in[6];
    const float* Wr2    = (const float*)d_in[7];

    const int N = in_sizes[0] / N_FEATS;           // 50000
    const int E = in_sizes[1] / 2;                 // 800000
    const int* src = ei;
    const int* dst = ei + E;

    const int NBKT = (N + NPBKT - 1) >> NBKT_SHIFT;  // 391 coarse buckets
    const int NB1  = (E + EPB - 1) / EPB;            // 196 split blocks
    const int NSTRIPS = (N + 63) / 64;               // 782 gemm strips

    // workspace layout
    char* ws = (char*)d_ws;
    size_t off = 0;
    int*            cursor     = (int*)(ws + off); off += align256((size_t)NBKT * sizeof(int));
    int*            counts     = (int*)(ws + off); off += align256((size_t)N * sizeof(int));
    int*            offsets    = (int*)(ws + off); off += align256((size_t)N * sizeof(int));
    unsigned short* Wc         = (unsigned short*)(ws + off); off += align256(64 * 32 * sizeof(unsigned short));
    float*          bvec       = (float*)(ws + off); off += align256(16 * sizeof(float));
    unsigned*       pairs      = (unsigned*)(ws + off); off += align256((size_t)NBKT * CAP * sizeof(unsigned));
    unsigned short* sorted_src = (unsigned short*)(ws + off); off += align256((size_t)NBKT * CAP * sizeof(unsigned short));
    unsigned*       G          = (unsigned*)(ws + off); off += align256((size_t)N * 16 * sizeof(unsigned short));
    float*          T          = (float*)(ws + off); off += align256((size_t)N * 16 * sizeof(float));
    unsigned*       pbf        = (unsigned*)(ws + off); off += align256((size_t)N * 4 * sizeof(unsigned));
    float*          q          = (float*)(ws + off); off += align256((size_t)N * 8 * sizeof(float));
    (void)ws_size;

    // 1. weight combine + cursor zero (tiny kernel, NOT memset)
    k_init<<<1, 256, 0, stream>>>(Wl1, bl1, Wr1, Wl2, bl2, Wr2, Wc, bvec,
                                  cursor, NBKT);
    // 2. bucket split (CAP regions) || MFMA GEMM
    k_split_gemm<<<NB1 + NSTRIPS, 256, 0, stream>>>(
        src, dst, cursor, pairs, E, NBKT, NB1,
        embeds, Wc, bvec, (unsigned short*)G, T, N, NSTRIPS);
    // 3. fused per-bucket sort + layer-1 gather -> pbf, q (+CSR for final)
    k_fsort_gather2<<<NBKT, 1024, 0, stream>>>(
        pairs, cursor, G, T, counts, offsets, sorted_src, pbf, q, N, NBKT);
    // 4. out = mean-gather(p) + q   (4 nodes/wave)
    k_final<<<(N + 15) / 16, 256, 0, stream>>>(pbf, q, counts, offsets,
                                               sorted_src, (float*)d_out, N);
}